// Round 5
// baseline (18367.725 us; speedup 1.0000x reference)
//
#include <hip/hip_runtime.h>
#include <hip/hip_bf16.h>

#define B_  32
#define T_  512
#define I_  512
#define H_  1024
#define O_  360
#define H3_ 3072
#define M_  (B_*T_)      // 16384

static constexpr int GRU_P    = 8;    // blocks per batch-group (barrier width)
static constexpr int GRU_NBLK = 16;   // 2 groups x 8 blocks

typedef __bf16 bf16x8 __attribute__((ext_vector_type(8)));
typedef float  f32x4  __attribute__((ext_vector_type(4)));

__device__ __forceinline__ float sigmoidf_(float x) {
  return 1.0f / (1.0f + __expf(-x));
}

__device__ __forceinline__ float ld_f32(const float* p) { return *p; }
__device__ __forceinline__ float ld_f32(const __hip_bfloat16* p) { return __bfloat162float(*p); }
__device__ __forceinline__ void st_f32(float* p, float v) { *p = v; }
__device__ __forceinline__ void st_f32(__hip_bfloat16* p, float v) { *p = __float2bfloat16(v); }

__device__ __forceinline__ unsigned short bf16_bits(float f) {
  __hip_bfloat16 b = __float2bfloat16(f);
  return *reinterpret_cast<unsigned short*>(&b);
}

// ---------------------------------------------------------------- utilities
__global__ void f32_to_bf16_k(const float* __restrict__ in,
                              __hip_bfloat16* __restrict__ out, int n) {
  int i = blockIdx.x * blockDim.x + threadIdx.x;
  int stride = gridDim.x * blockDim.x;
  for (; i < n; i += stride) out[i] = __float2bfloat16(in[i]);
}

__global__ void gru_init_k(__hip_bfloat16* __restrict__ hbuf,
                           unsigned* __restrict__ syncc) {
  int i = blockIdx.x * blockDim.x + threadIdx.x;
  int stride = gridDim.x * blockDim.x;
  for (; i < 2 * B_ * H_; i += stride) hbuf[i] = __float2bfloat16(0.0f);
  if (blockIdx.x == 0 && threadIdx.x == 0) { syncc[0] = 0u; syncc[64] = 0u; }
}

// ---------------------------------------------------------------- fp32 GEMM
// C[M,N] = act(A[M,K] * W[N,K]^T + bias[N]);  ACT=1 -> relu
// A row stride = lda. M multiple of 128; K multiple of 8; N arbitrary.
template <int ACT, typename OT>
__global__ __launch_bounds__(256)
void sgemm_bt(const float* __restrict__ A, const float* __restrict__ W,
              const float* __restrict__ bias, OT* __restrict__ C,
              int M, int N, int K, int lda) {
  __shared__ float As[8][128];
  __shared__ float Ws[8][128];
  const int tid = threadIdx.x;
  const int bm = blockIdx.y * 128;
  const int bn = blockIdx.x * 128;
  const int tm = ((tid >> 4) & 15) << 3;   // 0..120
  const int tn = (tid & 15) << 3;          // 0..120
  const int lr = tid >> 1;                 // 0..127 staging row
  const int lc = (tid & 1) << 2;           // 0 or 4 staging k-offset

  float acc[8][8];
#pragma unroll
  for (int i = 0; i < 8; ++i)
#pragma unroll
    for (int j = 0; j < 8; ++j) acc[i][j] = 0.0f;

  const float* Ap = A + (size_t)(bm + lr) * lda + lc;
  const bool wok = (bn + lr) < N;
  const float* Wp = W + (size_t)(wok ? (bn + lr) : 0) * K + lc;

  for (int k0 = 0; k0 < K; k0 += 8) {
    float4 av = *(const float4*)(Ap + k0);
    float4 wv = make_float4(0.f, 0.f, 0.f, 0.f);
    if (wok) wv = *(const float4*)(Wp + k0);
    __syncthreads();   // previous tile fully consumed
    As[lc + 0][lr] = av.x; As[lc + 1][lr] = av.y;
    As[lc + 2][lr] = av.z; As[lc + 3][lr] = av.w;
    Ws[lc + 0][lr] = wv.x; Ws[lc + 1][lr] = wv.y;
    Ws[lc + 2][lr] = wv.z; Ws[lc + 3][lr] = wv.w;
    __syncthreads();
#pragma unroll
    for (int kk = 0; kk < 8; ++kk) {
      float a[8], w[8];
#pragma unroll
      for (int i = 0; i < 8; ++i) a[i] = As[kk][tm + i];
#pragma unroll
      for (int j = 0; j < 8; ++j) w[j] = Ws[kk][tn + j];
#pragma unroll
      for (int i = 0; i < 8; ++i)
#pragma unroll
        for (int j = 0; j < 8; ++j) acc[i][j] = fmaf(a[i], w[j], acc[i][j]);
    }
  }

#pragma unroll
  for (int j = 0; j < 8; ++j) {
    const int n = bn + tn + j;
    if (n < N) {
      const float bj = bias[n];
#pragma unroll
      for (int i = 0; i < 8; ++i) {
        float v = acc[i][j] + bj;
        if (ACT) v = fmaxf(v, 0.0f);
        st_f32(&C[(size_t)(bm + tm + i) * N + n], v);
      }
    }
  }
}

// ---------------------------------------------------------------- GRU scan
// Batch rows are INDEPENDENT sequences -> split batch 32 into 2 groups of 16;
// each group is its own 8-block barrier domain (8 RMWs/step, not 64).
// 16 blocks x 256 threads. Block (group g = blockIdx/8, p = blockIdx%8) owns
// 128 hidden units [p*128, p*128+128) for the 16 batch rows of group g.
// Wave w owns 32 units (2 n-tiles of 16); M=16 = the group's batch rows.
// fp32 hidden state lives in registers; the bf16 copy is exchanged through
// L3 via relaxed sc1 atomics (no acq/rel -> no L2 flushes; W stays
// L2-resident at 2 blocks/XCD = 1.5 MiB of 4 MiB).
// hbuf layout: [group][2][16][1024] bf16. syncc: [group] at stride 64 u32.
// NOTE: xg and hs may ALIAS (fp32 path interleaves hs into xg's r columns);
// each (b,t,u) cell is read (prefetch, iter t-1) then written (iter t) by the
// SAME lane; neither pointer is __restrict__.
template <typename XT>
__global__ __launch_bounds__(256)
void gru_scan(const XT* xg,                            // [B,T,3H]
              const __hip_bfloat16* __restrict__ Wbf,  // [3H][H] bf16
              const float* __restrict__ bhh,           // [3H]
              float* hs, int hs_ld,                    // [B,T,*] out (row stride hs_ld)
              __hip_bfloat16* hbuf,                    // [2][2][16][H] bf16
              unsigned* syncc) {
  const int tid  = threadIdx.x;
  const int lane = tid & 63;
  const int wv   = tid >> 6;        // wave 0..3
  const int col  = lane & 15;
  const int krow = lane >> 4;       // 0..3
  const int g    = blockIdx.x >> 3; // batch group 0/1
  const int p    = blockIdx.x & 7;  // block in group
  const int u0   = p * 128 + wv * 32;
  const int u_0  = u0 + col;        // n-tile 0 unit
  const int u_1  = u0 + 16 + col;   // n-tile 1 unit
  const int bb   = krow * 4;        // batch-in-group base (+c)
  const int gb   = g * 16;          // group batch offset

  const float bhr0 = bhh[u_0],          bhr1 = bhh[u_1];
  const float bhz0 = bhh[H_ + u_0],     bhz1 = bhh[H_ + u_1];
  const float bhn0 = bhh[2 * H_ + u_0], bhn1 = bhh[2 * H_ + u_1];

  const bf16x8* Wv_ = (const bf16x8*)Wbf;      // 128 vectors per row
  const bf16x8* wr0 = Wv_ + (size_t)u_0 * 128 + krow;
  const bf16x8* wz0 = wr0 + (size_t)H_ * 128;
  const bf16x8* wn0 = wz0 + (size_t)H_ * 128;
  const bf16x8* wr1 = Wv_ + (size_t)u_1 * 128 + krow;
  const bf16x8* wz1 = wr1 + (size_t)H_ * 128;
  const bf16x8* wn1 = wz1 + (size_t)H_ * 128;

  unsigned* cnt = syncc + g * 64;   // per-group counter, 256 B apart

  f32x4 hold0 = {0.f, 0.f, 0.f, 0.f};
  f32x4 hold1 = {0.f, 0.f, 0.f, 0.f};

  // prefetch xg(t=0): 2 n-tiles x 3 gates x 4 batch rows
  float pxr0[4], pxz0[4], pxn0[4], pxr1[4], pxz1[4], pxn1[4];
#pragma unroll
  for (int c = 0; c < 4; ++c) {
    const XT* xp = xg + ((size_t)(gb + bb + c) * T_ + 0) * H3_;
    pxr0[c] = ld_f32(xp + u_0);           pxr1[c] = ld_f32(xp + u_1);
    pxz0[c] = ld_f32(xp + H_ + u_0);      pxz1[c] = ld_f32(xp + H_ + u_1);
    pxn0[c] = ld_f32(xp + 2 * H_ + u_0);  pxn1[c] = ld_f32(xp + 2 * H_ + u_1);
  }

  for (int t = 0; t < T_; ++t) {
    const int cur = t & 1;

    // ---- wait: all 8 blocks of this group have published h_{t-1}
    if (tid == 0) {
      const unsigned tgt = (unsigned)GRU_P * (unsigned)t;
      while (__hip_atomic_load(cnt, __ATOMIC_RELAXED, __HIP_MEMORY_SCOPE_AGENT) < tgt) {
      }
    }
    __syncthreads();

    // ---- recurrent matmul: A = group's h (16 x 1024 bf16) via relaxed
    //      agent-scope loads (L3-coherent); B = W_hh slice (L2-resident).
    const unsigned long long* ab =
        (const unsigned long long*)(hbuf + ((size_t)(g * 2 + cur)) * (16 * H_)) +
        (size_t)col * 256 + krow * 2;

    f32x4 ar0 = {0,0,0,0}, az0 = {0,0,0,0}, an0 = {0,0,0,0};
    f32x4 ar1 = {0,0,0,0}, az1 = {0,0,0,0}, an1 = {0,0,0,0};
#pragma unroll 8
    for (int ks = 0; ks < 32; ++ks) {
      union { unsigned long long q[2]; bf16x8 v; } A;
      A.q[0] = __hip_atomic_load(ab + ks * 8 + 0, __ATOMIC_RELAXED, __HIP_MEMORY_SCOPE_AGENT);
      A.q[1] = __hip_atomic_load(ab + ks * 8 + 1, __ATOMIC_RELAXED, __HIP_MEMORY_SCOPE_AGENT);
      ar0 = __builtin_amdgcn_mfma_f32_16x16x32_bf16(A.v, wr0[ks * 4], ar0, 0, 0, 0);
      az0 = __builtin_amdgcn_mfma_f32_16x16x32_bf16(A.v, wz0[ks * 4], az0, 0, 0, 0);
      an0 = __builtin_amdgcn_mfma_f32_16x16x32_bf16(A.v, wn0[ks * 4], an0, 0, 0, 0);
      ar1 = __builtin_amdgcn_mfma_f32_16x16x32_bf16(A.v, wr1[ks * 4], ar1, 0, 0, 0);
      az1 = __builtin_amdgcn_mfma_f32_16x16x32_bf16(A.v, wz1[ks * 4], az1, 0, 0, 0);
      an1 = __builtin_amdgcn_mfma_f32_16x16x32_bf16(A.v, wn1[ks * 4], an1, 0, 0, 0);
    }

    // ---- gates + state update (fp32 master state in registers)
    float hv0[4], hv1[4];
#pragma unroll
    for (int c = 0; c < 4; ++c) {
      const size_t hrow = ((size_t)(gb + bb + c) * T_ + t) * hs_ld;
      {
        const float r = sigmoidf_(pxr0[c] + ar0[c] + bhr0);
        const float z = sigmoidf_(pxz0[c] + az0[c] + bhz0);
        const float n = tanhf(pxn0[c] + r * (an0[c] + bhn0));
        const float h = (1.0f - z) * n + z * hold0[c];
        hold0[c] = h; hv0[c] = h;
        hs[hrow + u_0] = h;
      }
      {
        const float r = sigmoidf_(pxr1[c] + ar1[c] + bhr1);
        const float z = sigmoidf_(pxz1[c] + az1[c] + bhz1);
        const float n = tanhf(pxn1[c] + r * (an1[c] + bhn1));
        const float h = (1.0f - z) * n + z * hold1[c];
        hold1[c] = h; hv1[c] = h;
        hs[hrow + u_1] = h;
      }
    }

    // ---- publish bf16 h for next step (pack unit-pairs via lane^1 shuffle
    //      -> 32-bit relaxed atomic stores, sc1, to L3)
    unsigned* hn32 = (unsigned*)(hbuf + ((size_t)(g * 2 + (cur ^ 1))) * (16 * H_));
    const int c0 = (lane & 1) ? 2 : 0;   // even col stores c=0,1; odd c=2,3
#pragma unroll
    for (int c = 0; c < 4; ++c) {
      const float o0 = __shfl_xor(hv0[c], 1, 64);
      const float o1 = __shfl_xor(hv1[c], 1, 64);
      unsigned p0, p1;
      if (lane & 1) {
        p0 = (unsigned)bf16_bits(o0) | ((unsigned)bf16_bits(hv0[c]) << 16);
        p1 = (unsigned)bf16_bits(o1) | ((unsigned)bf16_bits(hv1[c]) << 16);
      } else {
        p0 = (unsigned)bf16_bits(hv0[c]) | ((unsigned)bf16_bits(o0) << 16);
        p1 = (unsigned)bf16_bits(hv1[c]) | ((unsigned)bf16_bits(o1) << 16);
      }
      if (c == c0 || c == c0 + 1) {
        __hip_atomic_store(hn32 + (size_t)(bb + c) * 512 + (u_0 >> 1), p0,
                           __ATOMIC_RELAXED, __HIP_MEMORY_SCOPE_AGENT);
        __hip_atomic_store(hn32 + (size_t)(bb + c) * 512 + (u_1 >> 1), p1,
                           __ATOMIC_RELAXED, __HIP_MEMORY_SCOPE_AGENT);
      }
    }

    // ---- drain publishes to L3, then arrive on the group counter
    asm volatile("s_waitcnt vmcnt(0)" ::: "memory");
    __syncthreads();
    if (tid == 0) {
      __hip_atomic_fetch_add(cnt, 1u, __ATOMIC_RELAXED, __HIP_MEMORY_SCOPE_AGENT);
    }

    // ---- prefetch xg(t+1); latency hides under the next barrier spin
    if (t + 1 < T_) {
#pragma unroll
      for (int c = 0; c < 4; ++c) {
        const XT* xp = xg + ((size_t)(gb + bb + c) * T_ + (t + 1)) * H3_;
        pxr0[c] = ld_f32(xp + u_0);           pxr1[c] = ld_f32(xp + u_1);
        pxz0[c] = ld_f32(xp + H_ + u_0);      pxz1[c] = ld_f32(xp + H_ + u_1);
        pxn0[c] = ld_f32(xp + 2 * H_ + u_0);  pxn1[c] = ld_f32(xp + 2 * H_ + u_1);
      }
    }
  }
}

// ---------------------------------------------------------------- launch
extern "C" void kernel_launch(void* const* d_in, const int* in_sizes, int n_in,
                              void* d_out, int out_size, void* d_ws, size_t ws_size,
                              hipStream_t stream) {
  const float* x    = (const float*)d_in[0];
  const float* W1   = (const float*)d_in[1];
  const float* b1   = (const float*)d_in[2];
  const float* W2   = (const float*)d_in[3];
  const float* b2   = (const float*)d_in[4];
  const float* Wih  = (const float*)d_in[5];
  const float* bih  = (const float*)d_in[6];
  const float* Whh  = (const float*)d_in[7];
  const float* bhh  = (const float*)d_in[8];
  const float* Wout = (const float*)d_in[9];
  const float* bout = (const float*)d_in[10];
  float* out = (float*)d_out;

  const size_t MB = (size_t)1 << 20;
  char* ws = (char*)d_ws;

  if (ws_size >= 256 * MB) {
    // ---------------- fp32-xg path (256 MiB) ----------------
    // [0,64M):   h2, later Wbf(6M)+hbuf(@8M)+syncc(@9M)
    // [64,256M): xg fp32 [M][3H]; h1 aliased at its start; hs interleaved in
    //            xg's r-gate columns (row stride 3H).
    float* h2 = (float*)ws;
    float* h1 = (float*)(ws + 64 * MB);
    float* xg = (float*)(ws + 64 * MB);
    __hip_bfloat16* Wbf  = (__hip_bfloat16*)ws;
    __hip_bfloat16* hbuf = (__hip_bfloat16*)(ws + 8 * MB);
    unsigned* syncc = (unsigned*)(ws + 9 * MB);
    float* hs = xg;  const int hs_ld = H3_;

    sgemm_bt<1, float><<<dim3(8, 128), 256, 0, stream>>>(x, W1, b1, h1, M_, H_, I_, I_);
    sgemm_bt<1, float><<<dim3(8, 128), 256, 0, stream>>>(h1, W2, b2, h2, M_, H_, H_, H_);
    sgemm_bt<0, float><<<dim3(24, 128), 256, 0, stream>>>(h2, Wih, bih, xg, M_, H3_, H_, H_);
    f32_to_bf16_k<<<768, 256, 0, stream>>>(Whh, Wbf, H3_ * H_);
    gru_init_k<<<32, 256, 0, stream>>>(hbuf, syncc);
    gru_scan<float><<<GRU_NBLK, 256, 0, stream>>>(xg, Wbf, bhh, hs, hs_ld, hbuf, syncc);
    sgemm_bt<0, float><<<dim3(3, 128), 256, 0, stream>>>(hs, Wout, bout, out, M_, O_, H_, hs_ld);
  } else if (ws_size >= 167 * MB) {
    // ---------------- bf16-xg fallback (167 MiB) ----------------
    float* h2 = (float*)ws;
    float* hs = (float*)ws;
    float* h1 = (float*)(ws + 64 * MB);
    __hip_bfloat16* xg   = (__hip_bfloat16*)(ws + 64 * MB);
    __hip_bfloat16* Wbf  = (__hip_bfloat16*)(ws + 160 * MB);
    __hip_bfloat16* hbuf = (__hip_bfloat16*)(ws + 166 * MB);
    unsigned* syncc = (unsigned*)(ws + 166 * MB + 256 * 1024);

    sgemm_bt<1, float><<<dim3(8, 128), 256, 0, stream>>>(x, W1, b1, h1, M_, H_, I_, I_);
    sgemm_bt<1, float><<<dim3(8, 128), 256, 0, stream>>>(h1, W2, b2, h2, M_, H_, H_, H_);
    sgemm_bt<0, __hip_bfloat16><<<dim3(24, 128), 256, 0, stream>>>(h2, Wih, bih, xg, M_, H3_, H_, H_);
    f32_to_bf16_k<<<768, 256, 0, stream>>>(Whh, Wbf, H3_ * H_);
    gru_init_k<<<32, 256, 0, stream>>>(hbuf, syncc);
    gru_scan<__hip_bfloat16><<<GRU_NBLK, 256, 0, stream>>>(xg, Wbf, bhh, hs, H_, hbuf, syncc);
    sgemm_bt<0, float><<<dim3(3, 128), 256, 0, stream>>>(hs, Wout, bout, out, M_, O_, H_, H_);
  }
  // else: insufficient workspace -> zeros (visible failure, tells us ws_size tier)
}

// Round 6
// 8845.075 us; speedup vs baseline: 2.0766x; 2.0766x over previous
//
#include <hip/hip_runtime.h>
#include <hip/hip_bf16.h>

#define B_  32
#define T_  512
#define I_  512
#define H_  1024
#define O_  360
#define H3_ 3072
#define M_  (B_*T_)      // 16384

static constexpr int GRU_NB = 64;   // blocks in GRU persistent kernel (16 units each)

typedef __bf16 bf16x8 __attribute__((ext_vector_type(8)));
typedef float  f32x4  __attribute__((ext_vector_type(4)));

__device__ __forceinline__ float sigmoidf_(float x) {
  return 1.0f / (1.0f + __expf(-x));
}

__device__ __forceinline__ float ld_f32(const float* p) { return *p; }
__device__ __forceinline__ float ld_f32(const __hip_bfloat16* p) { return __bfloat162float(*p); }
__device__ __forceinline__ void st_f32(float* p, float v) { *p = v; }
__device__ __forceinline__ void st_f32(__hip_bfloat16* p, float v) { *p = __float2bfloat16(v); }

__device__ __forceinline__ unsigned short bf16_bits(float f) {
  __hip_bfloat16 b = __float2bfloat16(f);
  return *reinterpret_cast<unsigned short*>(&b);
}

// ---------------------------------------------------------------- utilities
__global__ void f32_to_bf16_k(const float* __restrict__ in,
                              __hip_bfloat16* __restrict__ out, int n) {
  int i = blockIdx.x * blockDim.x + threadIdx.x;
  int stride = gridDim.x * blockDim.x;
  for (; i < n; i += stride) out[i] = __float2bfloat16(in[i]);
}

__global__ void gru_init_k(__hip_bfloat16* __restrict__ hbuf,
                           unsigned* __restrict__ tags) {
  int i = blockIdx.x * blockDim.x + threadIdx.x;
  int stride = gridDim.x * blockDim.x;
  for (; i < 2 * B_ * H_; i += stride) hbuf[i] = __float2bfloat16(0.0f);
  if (i < 128) tags[i] = 0u;   // covered: grid >= 128 threads
}

// ---------------------------------------------------------------- fp32 GEMM
// C[M,N] = act(A[M,K] * W[N,K]^T + bias[N]);  ACT=1 -> relu
// A row stride = lda. M multiple of 128; K multiple of 8; N arbitrary.
template <int ACT, typename OT>
__global__ __launch_bounds__(256)
void sgemm_bt(const float* __restrict__ A, const float* __restrict__ W,
              const float* __restrict__ bias, OT* __restrict__ C,
              int M, int N, int K, int lda) {
  __shared__ float As[8][128];
  __shared__ float Ws[8][128];
  const int tid = threadIdx.x;
  const int bm = blockIdx.y * 128;
  const int bn = blockIdx.x * 128;
  const int tm = ((tid >> 4) & 15) << 3;   // 0..120
  const int tn = (tid & 15) << 3;          // 0..120
  const int lr = tid >> 1;                 // 0..127 staging row
  const int lc = (tid & 1) << 2;           // 0 or 4 staging k-offset

  float acc[8][8];
#pragma unroll
  for (int i = 0; i < 8; ++i)
#pragma unroll
    for (int j = 0; j < 8; ++j) acc[i][j] = 0.0f;

  const float* Ap = A + (size_t)(bm + lr) * lda + lc;
  const bool wok = (bn + lr) < N;
  const float* Wp = W + (size_t)(wok ? (bn + lr) : 0) * K + lc;

  for (int k0 = 0; k0 < K; k0 += 8) {
    float4 av = *(const float4*)(Ap + k0);
    float4 wv = make_float4(0.f, 0.f, 0.f, 0.f);
    if (wok) wv = *(const float4*)(Wp + k0);
    __syncthreads();   // previous tile fully consumed
    As[lc + 0][lr] = av.x; As[lc + 1][lr] = av.y;
    As[lc + 2][lr] = av.z; As[lc + 3][lr] = av.w;
    Ws[lc + 0][lr] = wv.x; Ws[lc + 1][lr] = wv.y;
    Ws[lc + 2][lr] = wv.z; Ws[lc + 3][lr] = wv.w;
    __syncthreads();
#pragma unroll
    for (int kk = 0; kk < 8; ++kk) {
      float a[8], w[8];
#pragma unroll
      for (int i = 0; i < 8; ++i) a[i] = As[kk][tm + i];
#pragma unroll
      for (int j = 0; j < 8; ++j) w[j] = Ws[kk][tn + j];
#pragma unroll
      for (int i = 0; i < 8; ++i)
#pragma unroll
        for (int j = 0; j < 8; ++j) acc[i][j] = fmaf(a[i], w[j], acc[i][j]);
    }
  }

#pragma unroll
  for (int j = 0; j < 8; ++j) {
    const int n = bn + tn + j;
    if (n < N) {
      const float bj = bias[n];
#pragma unroll
      for (int i = 0; i < 8; ++i) {
        float v = acc[i][j] + bj;
        if (ACT) v = fmaxf(v, 0.0f);
        st_f32(&C[(size_t)(bm + tm + i) * N + n], v);
      }
    }
  }
}

// ---------------------------------------------------------------- GRU scan
// Persistent kernel: 64 blocks x 128 threads (2 waves). Block owns 16 hidden
// units; wave bt owns batch rows bt*16..bt*16+15 (full K = 1024).
// Synchronization: NO central counter, NO atomic RMW, NO __syncthreads.
// Each wave publishes its bf16 h half-slice (relaxed sc1 stores -> L3),
// drains vmcnt(0), then stores a per-wave tag = t+1. A consumer wave bt
// polls the 64 tags {tags[2j+bt]} (one lane each, single vector load per
// poll) and proceeds when all >= t. Lap-safety: overwriting hbuf[t&1] rows
// requires all same-bt waves to have published h_{t+1}, which implies they
// fully consumed those rows of h_t.
// NOTE: xg and hs may ALIAS (fp32 path interleaves hs into xg's r columns);
// each (b,t,u) cell is read (prefetch) then written (hs store) by the SAME
// lane; neither pointer is __restrict__.
template <typename XT>
__global__ __launch_bounds__(128)
void gru_scan(const XT* xg,                            // [B,T,3H]
              const __hip_bfloat16* __restrict__ Wbf,  // [3H][H] bf16
              const float* __restrict__ bhh,           // [3H]
              float* hs, int hs_ld,                    // [B,T,*] out (row stride hs_ld)
              __hip_bfloat16* hbuf,                    // [2][B][H] bf16
              unsigned* tags) {                        // [64 blocks][2 waves]
  const int tid  = threadIdx.x;
  const int lane = tid & 63;
  const int bt   = tid >> 6;        // wave index = b-tile (0/1)
  const int col  = lane & 15;       // unit within block / A row within tile
  const int krow = lane >> 4;       // k-octet selector (0..3)
  const int u    = blockIdx.x * 16 + col;
  const int bb   = bt * 16 + krow * 4;   // batch index base (+c)

  const float bhr = bhh[u];
  const float bhz = bhh[H_ + u];
  const float bhn = bhh[2 * H_ + u];

  const bf16x8* Wv = (const bf16x8*)Wbf;          // 128 vectors per row
  const bf16x8* wr = Wv + (size_t)u * 128 + krow;
  const bf16x8* wz = wr + (size_t)H_ * 128;
  const bf16x8* wn = wz + (size_t)H_ * 128;

  // this wave's poll address: tag of wave bt in block `lane`
  const unsigned* mytag = tags + ((lane << 1) | bt);
  // this wave's publish tag (lane 0 stores it)
  unsigned* ourtag = tags + ((blockIdx.x << 1) | bt);

  f32x4 hold = {0.f, 0.f, 0.f, 0.f};

  // prefetch xg(t=0)
  float pxr[4], pxz[4], pxn[4];
#pragma unroll
  for (int c = 0; c < 4; ++c) {
    const XT* xp = xg + ((size_t)(bb + c) * T_ + 0) * H3_;
    pxr[c] = ld_f32(xp + u);
    pxz[c] = ld_f32(xp + H_ + u);
    pxn[c] = ld_f32(xp + 2 * H_ + u);
  }

  for (int t = 0; t < T_; ++t) {
    const int cur = t & 1;

    // ---- wait: all producer waves of batch rows bt*16..+15 published h_t
    if (t > 0) {
      unsigned tg;
      do {
        tg = __hip_atomic_load(mytag, __ATOMIC_RELAXED, __HIP_MEMORY_SCOPE_AGENT);
      } while (__any(tg < (unsigned)t));
      __builtin_amdgcn_sched_barrier(0);
    }

    // ---- recurrent matmul: A (h_t, bf16) via relaxed agent-scope loads
    //      (sc1 -> L3-coherent); B (weights) cached, L2-resident.
    const unsigned long long* ab =
        (const unsigned long long*)(hbuf + cur * (B_ * H_)) +
        (size_t)(bt * 16 + col) * 256 + krow * 2;

    f32x4 ar = {0.f, 0.f, 0.f, 0.f};
    f32x4 az = {0.f, 0.f, 0.f, 0.f};
    f32x4 an = {0.f, 0.f, 0.f, 0.f};
#pragma unroll 8
    for (int ks = 0; ks < 32; ++ks) {
      union { unsigned long long q[2]; bf16x8 v; } A;
      A.q[0] = __hip_atomic_load(ab + ks * 8 + 0, __ATOMIC_RELAXED, __HIP_MEMORY_SCOPE_AGENT);
      A.q[1] = __hip_atomic_load(ab + ks * 8 + 1, __ATOMIC_RELAXED, __HIP_MEMORY_SCOPE_AGENT);
      ar = __builtin_amdgcn_mfma_f32_16x16x32_bf16(A.v, wr[ks * 4], ar, 0, 0, 0);
      az = __builtin_amdgcn_mfma_f32_16x16x32_bf16(A.v, wz[ks * 4], az, 0, 0, 0);
      an = __builtin_amdgcn_mfma_f32_16x16x32_bf16(A.v, wn[ks * 4], an, 0, 0, 0);
    }

    // ---- gates + state update (fp32 master state in registers)
    float hv[4];
#pragma unroll
    for (int c = 0; c < 4; ++c) {
      const float r = sigmoidf_(pxr[c] + ar[c] + bhr);
      const float z = sigmoidf_(pxz[c] + az[c] + bhz);
      const float n = tanhf(pxn[c] + r * (an[c] + bhn));
      const float h = (1.0f - z) * n + z * hold[c];
      hold[c] = h;
      hv[c] = h;
    }

    // ---- publish bf16 h_{t+1}: pack (u_even,u_odd) pairs via lane^1
    //      shuffle -> 32-bit relaxed atomic stores (sc1, to L3)
    unsigned* hn32 = (unsigned*)(hbuf + (cur ^ 1) * (B_ * H_));
    const int ue2 = (u & ~1) >> 1;           // u32 column index
    const int c0 = (lane & 1) ? 2 : 0;       // even lane stores c=0,1; odd c=2,3
#pragma unroll
    for (int c = 0; c < 4; ++c) {
      const float other = __shfl_xor(hv[c], 1, 64);
      unsigned p;
      if (lane & 1)
        p = (unsigned)bf16_bits(other) | ((unsigned)bf16_bits(hv[c]) << 16);
      else
        p = (unsigned)bf16_bits(hv[c]) | ((unsigned)bf16_bits(other) << 16);
      if (c == c0 || c == c0 + 1)
        __hip_atomic_store(hn32 + (size_t)(bb + c) * 512 + ue2, p,
                           __ATOMIC_RELAXED, __HIP_MEMORY_SCOPE_AGENT);
    }

    // ---- drain publish stores to L3, then raise our tag (plain store, no RMW)
    asm volatile("s_waitcnt vmcnt(0)" ::: "memory");
    if (lane == 0)
      __hip_atomic_store(ourtag, (unsigned)(t + 1),
                         __ATOMIC_RELAXED, __HIP_MEMORY_SCOPE_AGENT);

    // ---- off-critical-path work: hs stores (streaming) + xg(t+1) prefetch
#pragma unroll
    for (int c = 0; c < 4; ++c)
      hs[((size_t)(bb + c) * T_ + t) * hs_ld + u] = hv[c];

    if (t + 1 < T_) {
#pragma unroll
      for (int c = 0; c < 4; ++c) {
        const XT* xp = xg + ((size_t)(bb + c) * T_ + (t + 1)) * H3_;
        pxr[c] = ld_f32(xp + u);
        pxz[c] = ld_f32(xp + H_ + u);
        pxn[c] = ld_f32(xp + 2 * H_ + u);
      }
    }
  }
}

// ---------------------------------------------------------------- launch
extern "C" void kernel_launch(void* const* d_in, const int* in_sizes, int n_in,
                              void* d_out, int out_size, void* d_ws, size_t ws_size,
                              hipStream_t stream) {
  const float* x    = (const float*)d_in[0];
  const float* W1   = (const float*)d_in[1];
  const float* b1   = (const float*)d_in[2];
  const float* W2   = (const float*)d_in[3];
  const float* b2   = (const float*)d_in[4];
  const float* Wih  = (const float*)d_in[5];
  const float* bih  = (const float*)d_in[6];
  const float* Whh  = (const float*)d_in[7];
  const float* bhh  = (const float*)d_in[8];
  const float* Wout = (const float*)d_in[9];
  const float* bout = (const float*)d_in[10];
  float* out = (float*)d_out;

  const size_t MB = (size_t)1 << 20;
  char* ws = (char*)d_ws;

  if (ws_size >= 256 * MB) {
    // ---------------- fp32-xg path (256 MiB) ----------------
    // [0,64M):   h2, later Wbf(6M)+hbuf(@8M)+tags(@9M)
    // [64,256M): xg fp32 [M][3H]; h1 aliased at its start; hs interleaved in
    //            xg's r-gate columns (row stride 3H).
    float* h2 = (float*)ws;
    float* h1 = (float*)(ws + 64 * MB);
    float* xg = (float*)(ws + 64 * MB);
    __hip_bfloat16* Wbf  = (__hip_bfloat16*)ws;
    __hip_bfloat16* hbuf = (__hip_bfloat16*)(ws + 8 * MB);
    unsigned* tags = (unsigned*)(ws + 9 * MB);
    float* hs = xg;  const int hs_ld = H3_;

    sgemm_bt<1, float><<<dim3(8, 128), 256, 0, stream>>>(x, W1, b1, h1, M_, H_, I_, I_);
    sgemm_bt<1, float><<<dim3(8, 128), 256, 0, stream>>>(h1, W2, b2, h2, M_, H_, H_, H_);
    sgemm_bt<0, float><<<dim3(24, 128), 256, 0, stream>>>(h2, Wih, bih, xg, M_, H3_, H_, H_);
    f32_to_bf16_k<<<768, 256, 0, stream>>>(Whh, Wbf, H3_ * H_);
    gru_init_k<<<32, 256, 0, stream>>>(hbuf, tags);
    gru_scan<float><<<GRU_NB, 128, 0, stream>>>(xg, Wbf, bhh, hs, hs_ld, hbuf, tags);
    sgemm_bt<0, float><<<dim3(3, 128), 256, 0, stream>>>(hs, Wout, bout, out, M_, O_, H_, hs_ld);
  } else if (ws_size >= 167 * MB) {
    // ---------------- bf16-xg fallback (167 MiB) ----------------
    float* h2 = (float*)ws;
    float* hs = (float*)ws;
    float* h1 = (float*)(ws + 64 * MB);
    __hip_bfloat16* xg   = (__hip_bfloat16*)(ws + 64 * MB);
    __hip_bfloat16* Wbf  = (__hip_bfloat16*)(ws + 160 * MB);
    __hip_bfloat16* hbuf = (__hip_bfloat16*)(ws + 166 * MB);
    unsigned* tags = (unsigned*)(ws + 166 * MB + 256 * 1024);

    sgemm_bt<1, float><<<dim3(8, 128), 256, 0, stream>>>(x, W1, b1, h1, M_, H_, I_, I_);
    sgemm_bt<1, float><<<dim3(8, 128), 256, 0, stream>>>(h1, W2, b2, h2, M_, H_, H_, H_);
    sgemm_bt<0, __hip_bfloat16><<<dim3(24, 128), 256, 0, stream>>>(h2, Wih, bih, xg, M_, H3_, H_, H_);
    f32_to_bf16_k<<<768, 256, 0, stream>>>(Whh, Wbf, H3_ * H_);
    gru_init_k<<<32, 256, 0, stream>>>(hbuf, tags);
    gru_scan<__hip_bfloat16><<<GRU_NB, 128, 0, stream>>>(xg, Wbf, bhh, hs, H_, hbuf, tags);
    sgemm_bt<0, float><<<dim3(3, 128), 256, 0, stream>>>(hs, Wout, bout, out, M_, O_, H_, H_);
  }
  // else: insufficient workspace -> zeros (visible failure, tells us ws_size tier)
}

// Round 7
// 8710.842 us; speedup vs baseline: 2.1086x; 1.0154x over previous
//
#include <hip/hip_runtime.h>
#include <hip/hip_bf16.h>

#define B_  32
#define T_  512
#define I_  512
#define H_  1024
#define O_  360
#define H3_ 3072
#define M_  (B_*T_)      // 16384

typedef __bf16 bf16x8 __attribute__((ext_vector_type(8)));
typedef float  f32x4  __attribute__((ext_vector_type(4)));

__device__ __forceinline__ float sigmoidf_(float x) {
  return 1.0f / (1.0f + __expf(-x));
}

__device__ __forceinline__ float ld_f32(const float* p) { return *p; }
__device__ __forceinline__ float ld_f32(const __hip_bfloat16* p) { return __bfloat162float(*p); }
__device__ __forceinline__ void st_f32(float* p, float v) { *p = v; }
__device__ __forceinline__ void st_f32(__hip_bfloat16* p, float v) { *p = __float2bfloat16(v); }

// ---------------------------------------------------------------- utilities
__global__ void f32_to_bf16_k(const float* __restrict__ in,
                              __hip_bfloat16* __restrict__ out, int n) {
  int i = blockIdx.x * blockDim.x + threadIdx.x;
  int stride = gridDim.x * blockDim.x;
  for (; i < n; i += stride) out[i] = __float2bfloat16(in[i]);
}

__global__ void gru_init_k(__hip_bfloat16* __restrict__ hbuf) {
  int i = blockIdx.x * blockDim.x + threadIdx.x;
  int stride = gridDim.x * blockDim.x;
  for (; i < 2 * B_ * H_; i += stride) hbuf[i] = __float2bfloat16(0.0f);
}

// ---------------------------------------------------------------- fp32 GEMM
// C[M,N] = act(A[M,K] * W[N,K]^T + bias[N]);  ACT=1 -> relu
// A row stride = lda. M multiple of 128; K multiple of 8; N arbitrary.
template <int ACT, typename OT>
__global__ __launch_bounds__(256)
void sgemm_bt(const float* __restrict__ A, const float* __restrict__ W,
              const float* __restrict__ bias, OT* __restrict__ C,
              int M, int N, int K, int lda) {
  __shared__ float As[8][128];
  __shared__ float Ws[8][128];
  const int tid = threadIdx.x;
  const int bm = blockIdx.y * 128;
  const int bn = blockIdx.x * 128;
  const int tm = ((tid >> 4) & 15) << 3;   // 0..120
  const int tn = (tid & 15) << 3;          // 0..120
  const int lr = tid >> 1;                 // 0..127 staging row
  const int lc = (tid & 1) << 2;           // 0 or 4 staging k-offset

  float acc[8][8];
#pragma unroll
  for (int i = 0; i < 8; ++i)
#pragma unroll
    for (int j = 0; j < 8; ++j) acc[i][j] = 0.0f;

  const float* Ap = A + (size_t)(bm + lr) * lda + lc;
  const bool wok = (bn + lr) < N;
  const float* Wp = W + (size_t)(wok ? (bn + lr) : 0) * K + lc;

  for (int k0 = 0; k0 < K; k0 += 8) {
    float4 av = *(const float4*)(Ap + k0);
    float4 wv = make_float4(0.f, 0.f, 0.f, 0.f);
    if (wok) wv = *(const float4*)(Wp + k0);
    __syncthreads();   // previous tile fully consumed
    As[lc + 0][lr] = av.x; As[lc + 1][lr] = av.y;
    As[lc + 2][lr] = av.z; As[lc + 3][lr] = av.w;
    Ws[lc + 0][lr] = wv.x; Ws[lc + 1][lr] = wv.y;
    Ws[lc + 2][lr] = wv.z; Ws[lc + 3][lr] = wv.w;
    __syncthreads();
#pragma unroll
    for (int kk = 0; kk < 8; ++kk) {
      float a[8], w[8];
#pragma unroll
      for (int i = 0; i < 8; ++i) a[i] = As[kk][tm + i];
#pragma unroll
      for (int j = 0; j < 8; ++j) w[j] = Ws[kk][tn + j];
#pragma unroll
      for (int i = 0; i < 8; ++i)
#pragma unroll
        for (int j = 0; j < 8; ++j) acc[i][j] = fmaf(a[i], w[j], acc[i][j]);
    }
  }

#pragma unroll
  for (int j = 0; j < 8; ++j) {
    const int n = bn + tn + j;
    if (n < N) {
      const float bj = bias[n];
#pragma unroll
      for (int i = 0; i < 8; ++i) {
        float v = acc[i][j] + bj;
        if (ACT) v = fmaxf(v, 0.0f);
        st_f32(&C[(size_t)(bm + tm + i) * N + n], v);
      }
    }
  }
}

// ---------------------------------------------------------------- GRU step
// ONE timestep per kernel launch; the stream/graph dependency between
// launches IS the grid barrier (runtime-managed coherence -> all accesses
// are plain cached loads/stores; W_hh and hbuf stay L2-resident across
// dispatches). 64 blocks x 128 threads; block owns 16 hidden units, wave bt
// owns batch rows bt*16..+15 (full K=1024).
// State across launches: hbuf[2] bf16 ping-pong (A operand), hs fp32 (also
// the h_{t-1} source for the z*h term -> numerics identical to the register
// version).
// NOTE: xg and hs may ALIAS (fp32 path interleaves hs into xg's r columns);
// each (b,t,u) r-cell is read (xr) then written (hs) by the SAME lane.
template <typename XT>
__global__ __launch_bounds__(128)
void gru_step(const XT* xg,                            // [B,T,3H]
              const __hip_bfloat16* __restrict__ Wbf,  // [3H][H] bf16
              const float* __restrict__ bhh,           // [3H]
              float* hs, int hs_ld,                    // [B,T,*] out (row stride hs_ld)
              __hip_bfloat16* hbuf,                    // [2][B][H] bf16
              int t) {
  const int tid  = threadIdx.x;
  const int lane = tid & 63;
  const int bt   = tid >> 6;        // wave index = b-tile (0/1)
  const int col  = lane & 15;       // unit within block / A row within tile
  const int krow = lane >> 4;       // k-octet selector (0..3)
  const int u    = blockIdx.x * 16 + col;
  const int bb   = bt * 16 + krow * 4;   // batch index base (+c)
  const int cur  = t & 1;

  // ---- this step's input-gate projections (plain cached loads, L3-hot)
  float pxr[4], pxz[4], pxn[4], hold[4];
#pragma unroll
  for (int c = 0; c < 4; ++c) {
    const XT* xp = xg + ((size_t)(bb + c) * T_ + t) * H3_;
    pxr[c] = ld_f32(xp + u);
    pxz[c] = ld_f32(xp + H_ + u);
    pxn[c] = ld_f32(xp + 2 * H_ + u);
    hold[c] = (t == 0) ? 0.0f
            : hs[((size_t)(bb + c) * T_ + (t - 1)) * hs_ld + u];
  }

  const bf16x8* Wv = (const bf16x8*)Wbf;          // 128 vectors per row
  const bf16x8* wr = Wv + (size_t)u * 128 + krow;
  const bf16x8* wz = wr + (size_t)H_ * 128;
  const bf16x8* wn = wz + (size_t)H_ * 128;

  // ---- recurrent matmul: A = h_{t-1} bf16 (plain cached loads), B = W_hh
  const bf16x8* ap =
      (const bf16x8*)(hbuf + cur * (B_ * H_)) + (size_t)(bt * 16 + col) * 128 + krow;

  f32x4 ar = {0.f, 0.f, 0.f, 0.f};
  f32x4 az = {0.f, 0.f, 0.f, 0.f};
  f32x4 an = {0.f, 0.f, 0.f, 0.f};
#pragma unroll 8
  for (int ks = 0; ks < 32; ++ks) {
    bf16x8 a = ap[ks * 4];
    ar = __builtin_amdgcn_mfma_f32_16x16x32_bf16(a, wr[ks * 4], ar, 0, 0, 0);
    az = __builtin_amdgcn_mfma_f32_16x16x32_bf16(a, wz[ks * 4], az, 0, 0, 0);
    an = __builtin_amdgcn_mfma_f32_16x16x32_bf16(a, wn[ks * 4], an, 0, 0, 0);
  }

  const float bhr = bhh[u];
  const float bhz = bhh[H_ + u];
  const float bhn = bhh[2 * H_ + u];

  // ---- gates + state update; publish fp32 (hs) and bf16 (next A operand)
  __hip_bfloat16* hn_out = hbuf + (cur ^ 1) * (B_ * H_);
#pragma unroll
  for (int c = 0; c < 4; ++c) {
    const float r = sigmoidf_(pxr[c] + ar[c] + bhr);
    const float z = sigmoidf_(pxz[c] + az[c] + bhz);
    const float n = tanhf(pxn[c] + r * (an[c] + bhn));
    const float h = (1.0f - z) * n + z * hold[c];
    hs[((size_t)(bb + c) * T_ + t) * hs_ld + u] = h;
    hn_out[(bb + c) * H_ + u] = __float2bfloat16(h);
  }
}

// ---------------------------------------------------------------- launch
extern "C" void kernel_launch(void* const* d_in, const int* in_sizes, int n_in,
                              void* d_out, int out_size, void* d_ws, size_t ws_size,
                              hipStream_t stream) {
  const float* x    = (const float*)d_in[0];
  const float* W1   = (const float*)d_in[1];
  const float* b1   = (const float*)d_in[2];
  const float* W2   = (const float*)d_in[3];
  const float* b2   = (const float*)d_in[4];
  const float* Wih  = (const float*)d_in[5];
  const float* bih  = (const float*)d_in[6];
  const float* Whh  = (const float*)d_in[7];
  const float* bhh  = (const float*)d_in[8];
  const float* Wout = (const float*)d_in[9];
  const float* bout = (const float*)d_in[10];
  float* out = (float*)d_out;

  const size_t MB = (size_t)1 << 20;
  char* ws = (char*)d_ws;

  if (ws_size >= 256 * MB) {
    // ---------------- fp32-xg path (256 MiB) ----------------
    // [0,64M):   h2, later Wbf(6M)+hbuf(@8M)
    // [64,256M): xg fp32 [M][3H]; h1 aliased at its start; hs interleaved in
    //            xg's r-gate columns (row stride 3H).
    float* h2 = (float*)ws;
    float* h1 = (float*)(ws + 64 * MB);
    float* xg = (float*)(ws + 64 * MB);
    __hip_bfloat16* Wbf  = (__hip_bfloat16*)ws;
    __hip_bfloat16* hbuf = (__hip_bfloat16*)(ws + 8 * MB);
    float* hs = xg;  const int hs_ld = H3_;

    sgemm_bt<1, float><<<dim3(8, 128), 256, 0, stream>>>(x, W1, b1, h1, M_, H_, I_, I_);
    sgemm_bt<1, float><<<dim3(8, 128), 256, 0, stream>>>(h1, W2, b2, h2, M_, H_, H_, H_);
    sgemm_bt<0, float><<<dim3(24, 128), 256, 0, stream>>>(h2, Wih, bih, xg, M_, H3_, H_, H_);
    f32_to_bf16_k<<<768, 256, 0, stream>>>(Whh, Wbf, H3_ * H_);
    gru_init_k<<<32, 256, 0, stream>>>(hbuf);
    for (int t = 0; t < T_; ++t)
      gru_step<float><<<64, 128, 0, stream>>>(xg, Wbf, bhh, hs, hs_ld, hbuf, t);
    sgemm_bt<0, float><<<dim3(3, 128), 256, 0, stream>>>(hs, Wout, bout, out, M_, O_, H_, hs_ld);
  } else if (ws_size >= 167 * MB) {
    // ---------------- bf16-xg fallback (167 MiB) ----------------
    float* h2 = (float*)ws;
    float* hs = (float*)ws;
    float* h1 = (float*)(ws + 64 * MB);
    __hip_bfloat16* xg   = (__hip_bfloat16*)(ws + 64 * MB);
    __hip_bfloat16* Wbf  = (__hip_bfloat16*)(ws + 160 * MB);
    __hip_bfloat16* hbuf = (__hip_bfloat16*)(ws + 166 * MB);

    sgemm_bt<1, float><<<dim3(8, 128), 256, 0, stream>>>(x, W1, b1, h1, M_, H_, I_, I_);
    sgemm_bt<1, float><<<dim3(8, 128), 256, 0, stream>>>(h1, W2, b2, h2, M_, H_, H_, H_);
    sgemm_bt<0, __hip_bfloat16><<<dim3(24, 128), 256, 0, stream>>>(h2, Wih, bih, xg, M_, H3_, H_, H_);
    f32_to_bf16_k<<<768, 256, 0, stream>>>(Whh, Wbf, H3_ * H_);
    gru_init_k<<<32, 256, 0, stream>>>(hbuf);
    for (int t = 0; t < T_; ++t)
      gru_step<__hip_bfloat16><<<64, 128, 0, stream>>>(xg, Wbf, bhh, hs, H_, hbuf, t);
    sgemm_bt<0, float><<<dim3(3, 128), 256, 0, stream>>>(hs, Wout, bout, out, M_, O_, H_, H_);
  }
  // else: insufficient workspace -> zeros (visible failure, tells us ws_size tier)
}

// Round 8
// 8606.124 us; speedup vs baseline: 2.1343x; 1.0122x over previous
//
#include <hip/hip_runtime.h>
#include <hip/hip_bf16.h>

#define B_  32
#define T_  512
#define I_  512
#define H_  1024
#define O_  360
#define H3_ 3072
#define M_  (B_*T_)      // 16384

static constexpr int GRU_NB = 64;   // blocks in GRU persistent kernel (16 units each)

typedef __bf16 bf16x8 __attribute__((ext_vector_type(8)));
typedef float  f32x4  __attribute__((ext_vector_type(4)));

__device__ __forceinline__ float sigmoidf_(float x) {
  return 1.0f / (1.0f + __expf(-x));
}

__device__ __forceinline__ float ld_f32(const float* p) { return *p; }
__device__ __forceinline__ float ld_f32(const __hip_bfloat16* p) { return __bfloat162float(*p); }
__device__ __forceinline__ void st_f32(float* p, float v) { *p = v; }
__device__ __forceinline__ void st_f32(__hip_bfloat16* p, float v) { *p = __float2bfloat16(v); }

__device__ __forceinline__ unsigned short bf16_bits(float f) {
  __hip_bfloat16 b = __float2bfloat16(f);
  return *reinterpret_cast<unsigned short*>(&b);
}

// ---------------------------------------------------------------- utilities
__global__ void f32_to_bf16_k(const float* __restrict__ in,
                              __hip_bfloat16* __restrict__ out, int n) {
  int i = blockIdx.x * blockDim.x + threadIdx.x;
  int stride = gridDim.x * blockDim.x;
  for (; i < n; i += stride) out[i] = __float2bfloat16(in[i]);
}

__global__ void gru_init_k(__hip_bfloat16* __restrict__ hbuf,
                           unsigned* __restrict__ tags) {
  int i = blockIdx.x * blockDim.x + threadIdx.x;
  int stride = gridDim.x * blockDim.x;
  for (; i < 2 * B_ * H_; i += stride) hbuf[i] = __float2bfloat16(0.0f);
  if (i < 128) tags[i] = 0u;   // covered: grid >= 128 threads
}

// ---------------------------------------------------------------- fp32 GEMM
// C[M,N] = act(A[M,K] * W[N,K]^T + bias[N]);  ACT=1 -> relu
// A row stride = lda. M multiple of 128; K multiple of 8; N arbitrary.
template <int ACT, typename OT>
__global__ __launch_bounds__(256)
void sgemm_bt(const float* __restrict__ A, const float* __restrict__ W,
              const float* __restrict__ bias, OT* __restrict__ C,
              int M, int N, int K, int lda) {
  __shared__ float As[8][128];
  __shared__ float Ws[8][128];
  const int tid = threadIdx.x;
  const int bm = blockIdx.y * 128;
  const int bn = blockIdx.x * 128;
  const int tm = ((tid >> 4) & 15) << 3;   // 0..120
  const int tn = (tid & 15) << 3;          // 0..120
  const int lr = tid >> 1;                 // 0..127 staging row
  const int lc = (tid & 1) << 2;           // 0 or 4 staging k-offset

  float acc[8][8];
#pragma unroll
  for (int i = 0; i < 8; ++i)
#pragma unroll
    for (int j = 0; j < 8; ++j) acc[i][j] = 0.0f;

  const float* Ap = A + (size_t)(bm + lr) * lda + lc;
  const bool wok = (bn + lr) < N;
  const float* Wp = W + (size_t)(wok ? (bn + lr) : 0) * K + lc;

  for (int k0 = 0; k0 < K; k0 += 8) {
    float4 av = *(const float4*)(Ap + k0);
    float4 wv = make_float4(0.f, 0.f, 0.f, 0.f);
    if (wok) wv = *(const float4*)(Wp + k0);
    __syncthreads();   // previous tile fully consumed
    As[lc + 0][lr] = av.x; As[lc + 1][lr] = av.y;
    As[lc + 2][lr] = av.z; As[lc + 3][lr] = av.w;
    Ws[lc + 0][lr] = wv.x; Ws[lc + 1][lr] = wv.y;
    Ws[lc + 2][lr] = wv.z; Ws[lc + 3][lr] = wv.w;
    __syncthreads();
#pragma unroll
    for (int kk = 0; kk < 8; ++kk) {
      float a[8], w[8];
#pragma unroll
      for (int i = 0; i < 8; ++i) a[i] = As[kk][tm + i];
#pragma unroll
      for (int j = 0; j < 8; ++j) w[j] = Ws[kk][tn + j];
#pragma unroll
      for (int i = 0; i < 8; ++i)
#pragma unroll
        for (int j = 0; j < 8; ++j) acc[i][j] = fmaf(a[i], w[j], acc[i][j]);
    }
  }

#pragma unroll
  for (int j = 0; j < 8; ++j) {
    const int n = bn + tn + j;
    if (n < N) {
      const float bj = bias[n];
#pragma unroll
      for (int i = 0; i < 8; ++i) {
        float v = acc[i][j] + bj;
        if (ACT) v = fmaxf(v, 0.0f);
        st_f32(&C[(size_t)(bm + tm + i) * N + n], v);
      }
    }
  }
}

// ---------------------------------------------------------------- GRU scan
// R6 structure (64 blocks x 128 threads, data-flow tags, no RMW, no
// __syncthreads) + BUSY-SPIN FILLER: the poll loop issues the tag load,
// burns ~512 FMA cycles on dummy register chains while the load is in
// flight, then ballots. Purpose: keep every SIMD issuing continuously so
// the clock governor holds high sclk (testing the DVFS-derating theory of
// the ~13 us/step floor). Dummy chains are kept live via an asm sink; they
// touch no memory and cannot affect results.
// NOTE: xg and hs may ALIAS (fp32 path interleaves hs into xg's r columns);
// each (b,t,u) cell is read (prefetch) then written (hs store) by the SAME
// lane; neither pointer is __restrict__.
template <typename XT>
__global__ __launch_bounds__(128)
void gru_scan(const XT* xg,                            // [B,T,3H]
              const __hip_bfloat16* __restrict__ Wbf,  // [3H][H] bf16
              const float* __restrict__ bhh,           // [3H]
              float* hs, int hs_ld,                    // [B,T,*] out (row stride hs_ld)
              __hip_bfloat16* hbuf,                    // [2][B][H] bf16
              unsigned* tags) {                        // [64 blocks][2 waves]
  const int tid  = threadIdx.x;
  const int lane = tid & 63;
  const int bt   = tid >> 6;        // wave index = b-tile (0/1)
  const int col  = lane & 15;       // unit within block / A row within tile
  const int krow = lane >> 4;       // k-octet selector (0..3)
  const int u    = blockIdx.x * 16 + col;
  const int bb   = bt * 16 + krow * 4;   // batch index base (+c)

  const float bhr = bhh[u];
  const float bhz = bhh[H_ + u];
  const float bhn = bhh[2 * H_ + u];

  const bf16x8* Wv = (const bf16x8*)Wbf;          // 128 vectors per row
  const bf16x8* wr = Wv + (size_t)u * 128 + krow;
  const bf16x8* wz = wr + (size_t)H_ * 128;
  const bf16x8* wn = wz + (size_t)H_ * 128;

  // this wave's poll address: tag of wave bt in block `lane`
  const unsigned* mytag = tags + ((lane << 1) | bt);
  // this wave's publish tag (lane 0 stores it)
  unsigned* ourtag = tags + ((blockIdx.x << 1) | bt);

  f32x4 hold = {0.f, 0.f, 0.f, 0.f};

  // dummy busy-spin chains (live across the whole kernel; sunk at the end)
  float d0 = 1.0f, d1 = 1.1f, d2 = 1.2f, d3 = 1.3f;

  // prefetch xg(t=0)
  float pxr[4], pxz[4], pxn[4];
#pragma unroll
  for (int c = 0; c < 4; ++c) {
    const XT* xp = xg + ((size_t)(bb + c) * T_ + 0) * H3_;
    pxr[c] = ld_f32(xp + u);
    pxz[c] = ld_f32(xp + H_ + u);
    pxn[c] = ld_f32(xp + 2 * H_ + u);
  }

  for (int t = 0; t < T_; ++t) {
    const int cur = t & 1;

    // ---- wait: all producer waves of batch rows bt*16..+15 published h_t.
    //      Busy-spin: burn FMAs while each poll load is in flight.
    if (t > 0) {
      unsigned tg;
      do {
        tg = __hip_atomic_load(mytag, __ATOMIC_RELAXED, __HIP_MEMORY_SCOPE_AGENT);
#pragma unroll
        for (int i = 0; i < 128; ++i) {
          d0 = fmaf(d0, 0.9999999f, 1e-9f);
          d1 = fmaf(d1, 0.9999999f, 1e-9f);
          d2 = fmaf(d2, 0.9999999f, 1e-9f);
          d3 = fmaf(d3, 0.9999999f, 1e-9f);
        }
      } while (__any(tg < (unsigned)t));
      __builtin_amdgcn_sched_barrier(0);
    }

    // ---- recurrent matmul: A (h_t, bf16) via relaxed agent-scope loads
    //      (sc1 -> L3-coherent); B (weights) cached, L2-resident.
    const unsigned long long* ab =
        (const unsigned long long*)(hbuf + cur * (B_ * H_)) +
        (size_t)(bt * 16 + col) * 256 + krow * 2;

    f32x4 ar = {0.f, 0.f, 0.f, 0.f};
    f32x4 az = {0.f, 0.f, 0.f, 0.f};
    f32x4 an = {0.f, 0.f, 0.f, 0.f};
#pragma unroll 8
    for (int ks = 0; ks < 32; ++ks) {
      union { unsigned long long q[2]; bf16x8 v; } A;
      A.q[0] = __hip_atomic_load(ab + ks * 8 + 0, __ATOMIC_RELAXED, __HIP_MEMORY_SCOPE_AGENT);
      A.q[1] = __hip_atomic_load(ab + ks * 8 + 1, __ATOMIC_RELAXED, __HIP_MEMORY_SCOPE_AGENT);
      ar = __builtin_amdgcn_mfma_f32_16x16x32_bf16(A.v, wr[ks * 4], ar, 0, 0, 0);
      az = __builtin_amdgcn_mfma_f32_16x16x32_bf16(A.v, wz[ks * 4], az, 0, 0, 0);
      an = __builtin_amdgcn_mfma_f32_16x16x32_bf16(A.v, wn[ks * 4], an, 0, 0, 0);
    }

    // ---- gates + state update (fp32 master state in registers)
    float hv[4];
#pragma unroll
    for (int c = 0; c < 4; ++c) {
      const float r = sigmoidf_(pxr[c] + ar[c] + bhr);
      const float z = sigmoidf_(pxz[c] + az[c] + bhz);
      const float n = tanhf(pxn[c] + r * (an[c] + bhn));
      const float h = (1.0f - z) * n + z * hold[c];
      hold[c] = h;
      hv[c] = h;
    }

    // ---- publish bf16 h_{t+1}: pack (u_even,u_odd) pairs via lane^1
    //      shuffle -> 32-bit relaxed atomic stores (sc1, to L3)
    unsigned* hn32 = (unsigned*)(hbuf + (cur ^ 1) * (B_ * H_));
    const int ue2 = (u & ~1) >> 1;           // u32 column index
    const int c0 = (lane & 1) ? 2 : 0;       // even lane stores c=0,1; odd c=2,3
#pragma unroll
    for (int c = 0; c < 4; ++c) {
      const float other = __shfl_xor(hv[c], 1, 64);
      unsigned p;
      if (lane & 1)
        p = (unsigned)bf16_bits(other) | ((unsigned)bf16_bits(hv[c]) << 16);
      else
        p = (unsigned)bf16_bits(hv[c]) | ((unsigned)bf16_bits(other) << 16);
      if (c == c0 || c == c0 + 1)
        __hip_atomic_store(hn32 + (size_t)(bb + c) * 512 + ue2, p,
                           __ATOMIC_RELAXED, __HIP_MEMORY_SCOPE_AGENT);
    }

    // ---- drain publish stores to L3, then raise our tag (plain store, no RMW)
    asm volatile("s_waitcnt vmcnt(0)" ::: "memory");
    if (lane == 0)
      __hip_atomic_store(ourtag, (unsigned)(t + 1),
                         __ATOMIC_RELAXED, __HIP_MEMORY_SCOPE_AGENT);

    // ---- off-critical-path work: hs stores (streaming) + xg(t+1) prefetch
#pragma unroll
    for (int c = 0; c < 4; ++c)
      hs[((size_t)(bb + c) * T_ + t) * hs_ld + u] = hv[c];

    if (t + 1 < T_) {
#pragma unroll
      for (int c = 0; c < 4; ++c) {
        const XT* xp = xg + ((size_t)(bb + c) * T_ + (t + 1)) * H3_;
        pxr[c] = ld_f32(xp + u);
        pxz[c] = ld_f32(xp + H_ + u);
        pxn[c] = ld_f32(xp + 2 * H_ + u);
      }
    }
  }

  // keep the dummy chains alive (prevents DCE of the busy-spin)
  asm volatile("" :: "v"(d0), "v"(d1), "v"(d2), "v"(d3));
}

// ---------------------------------------------------------------- launch
extern "C" void kernel_launch(void* const* d_in, const int* in_sizes, int n_in,
                              void* d_out, int out_size, void* d_ws, size_t ws_size,
                              hipStream_t stream) {
  const float* x    = (const float*)d_in[0];
  const float* W1   = (const float*)d_in[1];
  const float* b1   = (const float*)d_in[2];
  const float* W2   = (const float*)d_in[3];
  const float* b2   = (const float*)d_in[4];
  const float* Wih  = (const float*)d_in[5];
  const float* bih  = (const float*)d_in[6];
  const float* Whh  = (const float*)d_in[7];
  const float* bhh  = (const float*)d_in[8];
  const float* Wout = (const float*)d_in[9];
  const float* bout = (const float*)d_in[10];
  float* out = (float*)d_out;

  const size_t MB = (size_t)1 << 20;
  char* ws = (char*)d_ws;

  if (ws_size >= 256 * MB) {
    // ---------------- fp32-xg path (256 MiB) ----------------
    // [0,64M):   h2, later Wbf(6M)+hbuf(@8M)+tags(@9M)
    // [64,256M): xg fp32 [M][3H]; h1 aliased at its start; hs interleaved in
    //            xg's r-gate columns (row stride 3H).
    float* h2 = (float*)ws;
    float* h1 = (float*)(ws + 64 * MB);
    float* xg = (float*)(ws + 64 * MB);
    __hip_bfloat16* Wbf  = (__hip_bfloat16*)ws;
    __hip_bfloat16* hbuf = (__hip_bfloat16*)(ws + 8 * MB);
    unsigned* tags = (unsigned*)(ws + 9 * MB);
    float* hs = xg;  const int hs_ld = H3_;

    sgemm_bt<1, float><<<dim3(8, 128), 256, 0, stream>>>(x, W1, b1, h1, M_, H_, I_, I_);
    sgemm_bt<1, float><<<dim3(8, 128), 256, 0, stream>>>(h1, W2, b2, h2, M_, H_, H_, H_);
    sgemm_bt<0, float><<<dim3(24, 128), 256, 0, stream>>>(h2, Wih, bih, xg, M_, H3_, H_, H_);
    f32_to_bf16_k<<<768, 256, 0, stream>>>(Whh, Wbf, H3_ * H_);
    gru_init_k<<<32, 256, 0, stream>>>(hbuf, tags);
    gru_scan<float><<<GRU_NB, 128, 0, stream>>>(xg, Wbf, bhh, hs, hs_ld, hbuf, tags);
    sgemm_bt<0, float><<<dim3(3, 128), 256, 0, stream>>>(hs, Wout, bout, out, M_, O_, H_, hs_ld);
  } else if (ws_size >= 167 * MB) {
    // ---------------- bf16-xg fallback (167 MiB) ----------------
    float* h2 = (float*)ws;
    float* hs = (float*)ws;
    float* h1 = (float*)(ws + 64 * MB);
    __hip_bfloat16* xg   = (__hip_bfloat16*)(ws + 64 * MB);
    __hip_bfloat16* Wbf  = (__hip_bfloat16*)(ws + 160 * MB);
    __hip_bfloat16* hbuf = (__hip_bfloat16*)(ws + 166 * MB);
    unsigned* tags = (unsigned*)(ws + 166 * MB + 256 * 1024);

    sgemm_bt<1, float><<<dim3(8, 128), 256, 0, stream>>>(x, W1, b1, h1, M_, H_, I_, I_);
    sgemm_bt<1, float><<<dim3(8, 128), 256, 0, stream>>>(h1, W2, b2, h2, M_, H_, H_, H_);
    sgemm_bt<0, __hip_bfloat16><<<dim3(24, 128), 256, 0, stream>>>(h2, Wih, bih, xg, M_, H3_, H_, H_);
    f32_to_bf16_k<<<768, 256, 0, stream>>>(Whh, Wbf, H3_ * H_);
    gru_init_k<<<32, 256, 0, stream>>>(hbuf, tags);
    gru_scan<__hip_bfloat16><<<GRU_NB, 128, 0, stream>>>(xg, Wbf, bhh, hs, H_, hbuf, tags);
    sgemm_bt<0, float><<<dim3(3, 128), 256, 0, stream>>>(hs, Wout, bout, out, M_, O_, H_, H_);
  }
  // else: insufficient workspace -> zeros (visible failure, tells us ws_size tier)
}